// Round 1
// baseline (2047.599 us; speedup 1.0000x reference)
//
#include <hip/hip_runtime.h>
#include <math.h>

#define HDIM 768
#define NHEAD 12
#define HEADD 64
#define FFDIM 3072
#define NEXP 4
#define SEQ 128
#define NB 64

__device__ __forceinline__ float gelu_tanh(float x) {
  float x3 = x * x * x;
  return 0.5f * x * (1.0f + tanhf(0.7978845608028654f * (x + 0.044715f * x3)));
}

// ---------------- routing: mean over seq, argmin distance to centers ----------
__global__ __launch_bounds__(256) void route_kernel(
    const float* __restrict__ hs, const float* __restrict__ centers,
    int* __restrict__ eid) {
  int b = blockIdx.x, t = threadIdx.x;
  __shared__ float hp[HDIM];
  __shared__ float dist[NEXP];
  const float* xb = hs + (size_t)b * SEQ * HDIM;
  for (int h = t; h < HDIM; h += 256) {
    float s = 0.f;
    for (int sq = 0; sq < SEQ; ++sq) s += xb[(size_t)sq * HDIM + h];
    hp[h] = s * (1.0f / SEQ);
  }
  if (t < NEXP) dist[t] = 0.f;
  __syncthreads();
  float pe[NEXP] = {0.f, 0.f, 0.f, 0.f};
  for (int h = t; h < HDIM; h += 256) {
    float v = hp[h];
#pragma unroll
    for (int e = 0; e < NEXP; ++e) {
      float d = v - centers[e * HDIM + h];
      pe[e] += d * d;
    }
  }
#pragma unroll
  for (int e = 0; e < NEXP; ++e) atomicAdd(&dist[e], pe[e]);
  __syncthreads();
  if (t == 0) {
    int best = 0; float bv = dist[0];
    for (int e = 1; e < NEXP; ++e) if (dist[e] < bv) { bv = dist[e]; best = e; }
    eid[b] = best;
  }
}

// ---------------- batched per-sample GEMM: C[b] = A[b] @ W[eid[b]] + bias ------
// A: [CB, SEQ, K]  W: [E, K, N]  bias: [E, N]  C: [CB, SEQ, N]
// block: 256 threads, tile 64x64, BK=16
template <int GELU>
__global__ __launch_bounds__(256) void gemm_bias_kernel(
    const float* __restrict__ A, const float* __restrict__ Wall,
    const float* __restrict__ Ball, const int* __restrict__ eid,
    float* __restrict__ C, int K, int N) {
  int b = blockIdx.z;
  int e = eid[b];
  const float* Ab = A + (size_t)b * SEQ * K;
  float* Cb = C + (size_t)b * SEQ * N;
  const float* W = Wall + (size_t)e * K * N;
  const float* bias = Ball + (size_t)e * N;

  __shared__ float As[16][68];  // [k][m], pad 68: float4-aligned + conflict-free
  __shared__ float Bs[16][64];  // [k][n]

  int t = threadIdx.x;
  int tx = t & 15, ty = t >> 4;
  int row0 = blockIdx.y * 64;
  int col0 = blockIdx.x * 64;

  // A tile load: thread -> (m = t>>2, kq = (t&3)*4), float4 along K
  int am = t >> 2, akq = (t & 3) << 2;
  // B tile load: thread -> (k = t>>4, n4 = (t&15)*4), float4 along N
  int bk = t >> 4, bn4 = (t & 15) << 2;

  const float* aptr = Ab + (size_t)(row0 + am) * K + akq;
  const float* bptr = W + (size_t)bk * N + col0 + bn4;

  float acc[4][4] = {};

  for (int k0 = 0; k0 < K; k0 += 16) {
    float4 av = *(const float4*)(aptr + k0);
    float4 bv = *(const float4*)(bptr + (size_t)k0 * N);
    As[akq + 0][am] = av.x;
    As[akq + 1][am] = av.y;
    As[akq + 2][am] = av.z;
    As[akq + 3][am] = av.w;
    *(float4*)&Bs[bk][bn4] = bv;
    __syncthreads();
#pragma unroll
    for (int kk = 0; kk < 16; ++kk) {
      float4 a = *(const float4*)&As[kk][ty << 2];
      float4 bb = *(const float4*)&Bs[kk][tx << 2];
      acc[0][0] += a.x * bb.x; acc[0][1] += a.x * bb.y; acc[0][2] += a.x * bb.z; acc[0][3] += a.x * bb.w;
      acc[1][0] += a.y * bb.x; acc[1][1] += a.y * bb.y; acc[1][2] += a.y * bb.z; acc[1][3] += a.y * bb.w;
      acc[2][0] += a.z * bb.x; acc[2][1] += a.z * bb.y; acc[2][2] += a.z * bb.z; acc[2][3] += a.z * bb.w;
      acc[3][0] += a.w * bb.x; acc[3][1] += a.w * bb.y; acc[3][2] += a.w * bb.z; acc[3][3] += a.w * bb.w;
    }
    __syncthreads();
  }

#pragma unroll
  for (int i = 0; i < 4; ++i) {
    int row = row0 + (ty << 2) + i;
    int col = col0 + (tx << 2);
    float4 o;
    o.x = acc[i][0] + bias[col + 0];
    o.y = acc[i][1] + bias[col + 1];
    o.z = acc[i][2] + bias[col + 2];
    o.w = acc[i][3] + bias[col + 3];
    if (GELU) {
      o.x = gelu_tanh(o.x); o.y = gelu_tanh(o.y);
      o.z = gelu_tanh(o.z); o.w = gelu_tanh(o.w);
    }
    *(float4*)(Cb + (size_t)row * N + col) = o;
  }
}

// ---------------- attention: one block per (sample, head, 32-row q tile) -------
__global__ __launch_bounds__(256) void attn_kernel(
    const float* __restrict__ Q, const float* __restrict__ Kb,
    const float* __restrict__ Vb, const float* __restrict__ mask,
    int b0, float* __restrict__ Ctx) {
  int b = blockIdx.z;   // chunk-local sample
  int h = blockIdx.y;   // head
  int q0 = blockIdx.x * 32;
  int t = threadIdx.x;

  __shared__ float qs[32][68];
  __shared__ float ks[128][68];   // K, then reused for V
  __shared__ float ss[32][129];

  size_t base = (size_t)b * SEQ * HDIM + (size_t)h * HEADD;

  for (int idx = t; idx < 32 * 64; idx += 256) {
    int i = idx >> 6, d = idx & 63;
    qs[i][d] = Q[base + (size_t)(q0 + i) * HDIM + d];
  }
  for (int idx = t; idx < 128 * 64; idx += 256) {
    int j = idx >> 6, d = idx & 63;
    ks[j][d] = Kb[base + (size_t)j * HDIM + d];
  }
  __syncthreads();

  // scores: thread -> qi = t>>3 (0..31), g = t&7; j = jj*8+g, jj=0..15
  {
    int qi = t >> 3, g = t & 7;
    const float* mrow = mask + (size_t)(b0 + b) * SEQ;
    float acc[16];
#pragma unroll
    for (int jj = 0; jj < 16; ++jj) acc[jj] = 0.f;
#pragma unroll
    for (int d4 = 0; d4 < 16; ++d4) {
      float4 q4 = *(const float4*)&qs[qi][d4 << 2];
#pragma unroll
      for (int jj = 0; jj < 16; ++jj) {
        float4 k4 = *(const float4*)&ks[jj * 8 + g][d4 << 2];
        acc[jj] += q4.x * k4.x + q4.y * k4.y + q4.z * k4.z + q4.w * k4.w;
      }
    }
#pragma unroll
    for (int jj = 0; jj < 16; ++jj) {
      int j = jj * 8 + g;
      ss[qi][j] = acc[jj] * 0.125f + mrow[j];
    }
  }
  __syncthreads();

  // softmax over keys, one thread per row
  if (t < 32) {
    float m = -1e30f;
    for (int j = 0; j < 128; ++j) m = fmaxf(m, ss[t][j]);
    float sum = 0.f;
    for (int j = 0; j < 128; ++j) {
      float ev = __expf(ss[t][j] - m);
      ss[t][j] = ev;
      sum += ev;
    }
    float inv = 1.f / sum;
    for (int j = 0; j < 128; ++j) ss[t][j] *= inv;
  }
  __syncthreads();

  // load V into ks region
  for (int idx = t; idx < 128 * 64; idx += 256) {
    int j = idx >> 6, d = idx & 63;
    ks[j][d] = Vb[base + (size_t)j * HDIM + d];
  }
  __syncthreads();

  // PV: thread -> i = t>>3, d8 = (t&7)*8 (8 output cols as 2 float4)
  {
    int i = t >> 3, d8 = (t & 7) << 3;
    float4 a0 = {0.f, 0.f, 0.f, 0.f}, a1 = {0.f, 0.f, 0.f, 0.f};
#pragma unroll 4
    for (int j = 0; j < 128; ++j) {
      float p = ss[i][j];
      float4 v0 = *(const float4*)&ks[j][d8];
      float4 v1 = *(const float4*)&ks[j][d8 + 4];
      a0.x += p * v0.x; a0.y += p * v0.y; a0.z += p * v0.z; a0.w += p * v0.w;
      a1.x += p * v1.x; a1.y += p * v1.y; a1.z += p * v1.z; a1.w += p * v1.w;
    }
    float* op = Ctx + base + (size_t)(q0 + i) * HDIM + d8;
    *(float4*)op = a0;
    *(float4*)(op + 4) = a1;
  }
}

// ---------------- residual + layernorm: one block per row ---------------------
__global__ __launch_bounds__(256) void resid_ln_kernel(
    const float* __restrict__ X, const float* __restrict__ Y,
    const float* __restrict__ Gall, const float* __restrict__ Ball,
    const int* __restrict__ eid, float* __restrict__ Out) {
  int row = blockIdx.x, b = blockIdx.y, t = threadIdx.x;
  int e = eid[b];
  const float* x = X + ((size_t)b * SEQ + row) * HDIM;
  const float* y = Y + ((size_t)b * SEQ + row) * HDIM;
  float* o = Out + ((size_t)b * SEQ + row) * HDIM;
  const float* g = Gall + (size_t)e * HDIM;
  const float* bb = Ball + (size_t)e * HDIM;

  __shared__ float buf[HDIM];
  __shared__ float red[256];

  float s = 0.f;
  for (int h = t; h < HDIM; h += 256) {
    float v = x[h] + y[h];
    buf[h] = v;
    s += v;
  }
  red[t] = s;
  __syncthreads();
  for (int off = 128; off > 0; off >>= 1) {
    if (t < off) red[t] += red[t + off];
    __syncthreads();
  }
  float mean = red[0] * (1.0f / HDIM);
  __syncthreads();

  float s2 = 0.f;
  for (int h = t; h < HDIM; h += 256) {
    float d = buf[h] - mean;
    s2 += d * d;
  }
  red[t] = s2;
  __syncthreads();
  for (int off = 128; off > 0; off >>= 1) {
    if (t < off) red[t] += red[t + off];
    __syncthreads();
  }
  float var = red[0] * (1.0f / HDIM);
  float rs = rsqrtf(var + 1e-12f);

  for (int h = t; h < HDIM; h += 256) {
    o[h] = (buf[h] - mean) * rs * g[h] + bb[h];
  }
}

// ------------------------------------------------------------------------------
extern "C" void kernel_launch(void* const* d_in, const int* in_sizes, int n_in,
                              void* d_out, int out_size, void* d_ws, size_t ws_size,
                              hipStream_t stream) {
  const float* hs   = (const float*)d_in[0];   // [64,128,768]
  const float* mask = (const float*)d_in[1];   // [64,128]
  const float* cen  = (const float*)d_in[2];   // [4,768]
  const float* wq = (const float*)d_in[3];
  const float* wk = (const float*)d_in[4];
  const float* wv = (const float*)d_in[5];
  const float* wo = (const float*)d_in[6];
  const float* bq = (const float*)d_in[7];
  const float* bk = (const float*)d_in[8];
  const float* bv = (const float*)d_in[9];
  const float* bo = (const float*)d_in[10];
  const float* ln1g = (const float*)d_in[11];
  const float* ln1b = (const float*)d_in[12];
  const float* w1 = (const float*)d_in[13];
  const float* b1 = (const float*)d_in[14];
  const float* w2 = (const float*)d_in[15];
  const float* b2 = (const float*)d_in[16];
  const float* ln2g = (const float*)d_in[17];
  const float* ln2b = (const float*)d_in[18];
  float* out = (float*)d_out;

  int* eid = (int*)d_ws;
  float* basep = (float*)((char*)d_ws + 256);
  const size_t sh = (size_t)SEQ * HDIM;                       // 98304
  const size_t perCB = (5 * sh + (size_t)SEQ * FFDIM) * 4;    // bytes/sample
  int CB = 64;
  while (CB > 1 && (size_t)CB * perCB + 256 > ws_size) CB >>= 1;

  route_kernel<<<NB, 256, 0, stream>>>(hs, cen, eid);

  float* qb  = basep;
  float* kb  = qb + (size_t)CB * sh;
  float* vb  = kb + (size_t)CB * sh;
  float* cxb = vb + (size_t)CB * sh;
  float* aob = cxb + (size_t)CB * sh;
  float* ffb = aob + (size_t)CB * sh;   // CB * SEQ * FFDIM

  for (int b0 = 0; b0 < NB; b0 += CB) {
    const float* hsc = hs + (size_t)b0 * sh;
    const int* ec = eid + b0;
    dim3 g768(HDIM / 64, SEQ / 64, CB);
    // QKV
    gemm_bias_kernel<0><<<g768, 256, 0, stream>>>(hsc, wq, bq, ec, qb, HDIM, HDIM);
    gemm_bias_kernel<0><<<g768, 256, 0, stream>>>(hsc, wk, bk, ec, kb, HDIM, HDIM);
    gemm_bias_kernel<0><<<g768, 256, 0, stream>>>(hsc, wv, bv, ec, vb, HDIM, HDIM);
    // attention -> cxb
    attn_kernel<<<dim3(SEQ / 32, NHEAD, CB), 256, 0, stream>>>(qb, kb, vb, mask, b0, cxb);
    // wo -> qb (reuse), then LN1 -> aob
    gemm_bias_kernel<0><<<g768, 256, 0, stream>>>(cxb, wo, bo, ec, qb, HDIM, HDIM);
    resid_ln_kernel<<<dim3(SEQ, CB), 256, 0, stream>>>(hsc, qb, ln1g, ln1b, ec, aob);
    // FFN: w1+gelu -> ffb, w2 -> vb (reuse), LN2 -> out
    gemm_bias_kernel<1><<<dim3(FFDIM / 64, SEQ / 64, CB), 256, 0, stream>>>(aob, w1, b1, ec, ffb, HDIM, FFDIM);
    gemm_bias_kernel<0><<<g768, 256, 0, stream>>>(ffb, w2, b2, ec, vb, FFDIM, HDIM);
    resid_ln_kernel<<<dim3(SEQ, CB), 256, 0, stream>>>(aob, vb, ln2g, ln2b, ec, out + (size_t)b0 * sh);
  }
}

// Round 2
// 654.480 us; speedup vs baseline: 3.1286x; 3.1286x over previous
//
#include <hip/hip_runtime.h>
#include <hip/hip_bf16.h>
#include <math.h>

#define HDIM 768
#define NHEAD 12
#define HEADD 64
#define FFDIM 3072
#define NEXP 4
#define SEQ 128
#define NB 64
#define QKVN 2304

typedef __attribute__((ext_vector_type(8))) _Float16 f16x8;
typedef __attribute__((ext_vector_type(4))) float f32x4;
typedef unsigned short u16;

__device__ __forceinline__ float gelu_tanh(float x) {
  float x3 = x * x * x;
  return 0.5f * x * (1.0f + tanhf(0.7978845608028654f * (x + 0.044715f * x3)));
}

__device__ __forceinline__ void gld_lds16(const void* g, void* l) {
  __builtin_amdgcn_global_load_lds(
      (const __attribute__((address_space(1))) unsigned int*)g,
      (__attribute__((address_space(3))) unsigned int*)l, 16, 0, 0);
}

// ---------------- routing ----------------------------------------------------
__global__ __launch_bounds__(256) void route_kernel(
    const float* __restrict__ hs, const float* __restrict__ centers,
    int* __restrict__ eid) {
  int b = blockIdx.x, t = threadIdx.x;
  __shared__ float hp[HDIM];
  __shared__ float dist[NEXP];
  const float* xb = hs + (size_t)b * SEQ * HDIM;
  for (int h = t; h < HDIM; h += 256) {
    float s = 0.f;
    for (int sq = 0; sq < SEQ; ++sq) s += xb[(size_t)sq * HDIM + h];
    hp[h] = s * (1.0f / SEQ);
  }
  if (t < NEXP) dist[t] = 0.f;
  __syncthreads();
  float pe[NEXP] = {0.f, 0.f, 0.f, 0.f};
  for (int h = t; h < HDIM; h += 256) {
    float v = hp[h];
#pragma unroll
    for (int e = 0; e < NEXP; ++e) {
      float d = v - centers[e * HDIM + h];
      pe[e] += d * d;
    }
  }
#pragma unroll
  for (int e = 0; e < NEXP; ++e) atomicAdd(&dist[e], pe[e]);
  __syncthreads();
  if (t == 0) {
    int best = 0; float bv = dist[0];
    for (int e = 1; e < NEXP; ++e) if (dist[e] < bv) { bv = dist[e]; best = e; }
    eid[b] = best;
  }
}

// ---------------- fp32 -> f16 elementwise ------------------------------------
__global__ __launch_bounds__(256) void cvt_f16(const float* __restrict__ in,
                                               _Float16* __restrict__ out, int n4) {
  int i = blockIdx.x * 256 + threadIdx.x;
  if (i < n4) {
    float4 v = ((const float4*)in)[i];
    out[i * 4 + 0] = (_Float16)v.x;
    out[i * 4 + 1] = (_Float16)v.y;
    out[i * 4 + 2] = (_Float16)v.z;
    out[i * 4 + 3] = (_Float16)v.w;
  }
}

// ---------------- weight transpose+convert: [E][K][N] f32 -> [E][N][K] f16 ----
__global__ __launch_bounds__(256) void transpose_cvt(
    const float* __restrict__ in, _Float16* __restrict__ out,
    int K, int N, size_t outEstride) {
  __shared__ float tile[32][33];
  int e = blockIdx.z;
  const float* ip = in + (size_t)e * K * N;
  _Float16* op = out + (size_t)e * outEstride;
  int nb = blockIdx.x * 32, kb = blockIdx.y * 32;
  int tx = threadIdx.x & 31, ty = threadIdx.x >> 5;
  for (int i = ty; i < 32; i += 8)
    tile[i][tx] = ip[(size_t)(kb + i) * N + nb + tx];
  __syncthreads();
  for (int i = ty; i < 32; i += 8)
    op[(size_t)(nb + i) * K + kb + tx] = (_Float16)tile[tx][i];
}

__global__ __launch_bounds__(256) void concat_bias(
    const float* __restrict__ bq, const float* __restrict__ bk,
    const float* __restrict__ bv, float* __restrict__ bqkv) {
  int i = blockIdx.x * 256 + threadIdx.x;
  if (i < NEXP * QKVN) {
    int e = i / QKVN, n = i % QKVN;
    float v = (n < HDIM) ? bq[e * HDIM + n]
            : (n < 2 * HDIM) ? bk[e * HDIM + n - HDIM]
                             : bv[e * HDIM + n - 2 * HDIM];
    bqkv[i] = v;
  }
}

// ---------------- MFMA GEMM: C[b] = A[b] @ Wt[eid[b]]^T + bias ----------------
// A: [B][128][K] f16 row-major; Wt: [E][N][K] f16 (K-contiguous); C: [B][128][N]
// 128x128 tile, BK=32, 4 waves each 64x64 via 4x4 mfma_f32_16x16x32_f16
template <int OUT_F16, int GELU>
__global__ __launch_bounds__(256) void gemm_mfma(
    const _Float16* __restrict__ A, const _Float16* __restrict__ Wt,
    const float* __restrict__ Ball, const int* __restrict__ eid,
    void* __restrict__ Cv, int K, int N) {
  int b = blockIdx.z;
  int e = eid[b];
  int col0 = blockIdx.x * 128;
  int t = threadIdx.x;
  int lane = t & 63, w = t >> 6;
  int quad = lane >> 4, l16 = lane & 15;
  int wr = (w >> 1) * 64, wc = (w & 1) * 64;

  __shared__ __align__(16) _Float16 As[128 * 32];
  __shared__ __align__(16) _Float16 Bs[128 * 32];

  const _Float16* Ab = A + (size_t)b * SEQ * K;
  const _Float16* Wb = Wt + (size_t)e * N * K + (size_t)col0 * K;

  // staging map: issue i, elem = i*2048 + t*8 -> m = elem>>5, kk = elem&31
  int e0 = t * 8, e1 = 2048 + t * 8;
  int m0 = e0 >> 5, k0e = e0 & 31;
  int m1 = e1 >> 5, k1e = e1 & 31;
  const _Float16* ga0 = Ab + (size_t)m0 * K + k0e;
  const _Float16* ga1 = Ab + (size_t)m1 * K + k1e;
  const _Float16* gb0 = Wb + (size_t)m0 * K + k0e;
  const _Float16* gb1 = Wb + (size_t)m1 * K + k1e;
  _Float16* lA0 = &As[e0]; _Float16* lA1 = &As[e1];
  _Float16* lB0 = &Bs[e0]; _Float16* lB1 = &Bs[e1];

  f32x4 acc[4][4];
#pragma unroll
  for (int i = 0; i < 4; ++i)
#pragma unroll
    for (int j = 0; j < 4; ++j) acc[i][j] = (f32x4){0.f, 0.f, 0.f, 0.f};

  for (int kk = 0; kk < K; kk += 32) {
    gld_lds16(ga0 + kk, lA0);
    gld_lds16(ga1 + kk, lA1);
    gld_lds16(gb0 + kk, lB0);
    gld_lds16(gb1 + kk, lB1);
    __syncthreads();
    f16x8 af[4], bf[4];
#pragma unroll
    for (int i = 0; i < 4; ++i)
      af[i] = *(const f16x8*)&As[(wr + i * 16 + l16) * 32 + quad * 8];
#pragma unroll
    for (int i = 0; i < 4; ++i)
      bf[i] = *(const f16x8*)&Bs[(wc + i * 16 + l16) * 32 + quad * 8];
#pragma unroll
    for (int i = 0; i < 4; ++i)
#pragma unroll
      for (int j = 0; j < 4; ++j)
        acc[i][j] = __builtin_amdgcn_mfma_f32_16x16x32_f16(af[i], bf[j], acc[i][j], 0, 0, 0);
    __syncthreads();
  }

  const float* bias = Ball + (size_t)e * N;
  float* Cf = (float*)Cv + (size_t)b * SEQ * N;
  _Float16* Ch = (_Float16*)Cv + (size_t)b * SEQ * N;
#pragma unroll
  for (int i = 0; i < 4; ++i) {
#pragma unroll
    for (int j = 0; j < 4; ++j) {
      int col = col0 + wc + j * 16 + l16;
      float bv = bias[col];
#pragma unroll
      for (int r = 0; r < 4; ++r) {
        int row = wr + i * 16 + quad * 4 + r;
        float v = acc[i][j][r] + bv;
        if (GELU) v = gelu_tanh(v);
        if (OUT_F16) Ch[(size_t)row * N + col] = (_Float16)v;
        else Cf[(size_t)row * N + col] = v;
      }
    }
  }
}

// ---------------- attention: f16 QKV (fused [b][128][2304]), f16 ctx out ------
__global__ __launch_bounds__(256) void attn_kernel(
    const _Float16* __restrict__ QKV, const float* __restrict__ mask,
    int b0, _Float16* __restrict__ Ctx) {
  int b = blockIdx.z, h = blockIdx.y, q0 = blockIdx.x * 32, t = threadIdx.x;

  __shared__ float qs[32][68];
  __shared__ float ks[128][68];
  __shared__ float ss[32][129];

  const _Float16* Qb = QKV + (size_t)b * SEQ * QKVN + h * HEADD;
  const _Float16* Kb = Qb + HDIM;
  const _Float16* Vb = Qb + 2 * HDIM;

  for (int idx = t; idx < 32 * 64; idx += 256) {
    int i = idx >> 6, d = idx & 63;
    qs[i][d] = (float)Qb[(size_t)(q0 + i) * QKVN + d];
  }
  for (int idx = t; idx < 128 * 64; idx += 256) {
    int j = idx >> 6, d = idx & 63;
    ks[j][d] = (float)Kb[(size_t)j * QKVN + d];
  }
  __syncthreads();

  {
    int qi = t >> 3, g = t & 7;
    const float* mrow = mask + (size_t)(b0 + b) * SEQ;
    float acc[16];
#pragma unroll
    for (int jj = 0; jj < 16; ++jj) acc[jj] = 0.f;
#pragma unroll
    for (int d4 = 0; d4 < 16; ++d4) {
      float4 q4 = *(const float4*)&qs[qi][d4 << 2];
#pragma unroll
      for (int jj = 0; jj < 16; ++jj) {
        float4 k4 = *(const float4*)&ks[jj * 8 + g][d4 << 2];
        acc[jj] += q4.x * k4.x + q4.y * k4.y + q4.z * k4.z + q4.w * k4.w;
      }
    }
#pragma unroll
    for (int jj = 0; jj < 16; ++jj) {
      int j = jj * 8 + g;
      ss[qi][j] = acc[jj] * 0.125f + mrow[j];
    }
  }
  __syncthreads();

  if (t < 32) {
    float m = -1e30f;
    for (int j = 0; j < 128; ++j) m = fmaxf(m, ss[t][j]);
    float sum = 0.f;
    for (int j = 0; j < 128; ++j) {
      float ev = __expf(ss[t][j] - m);
      ss[t][j] = ev;
      sum += ev;
    }
    float inv = 1.f / sum;
    for (int j = 0; j < 128; ++j) ss[t][j] *= inv;
  }
  __syncthreads();

  for (int idx = t; idx < 128 * 64; idx += 256) {
    int j = idx >> 6, d = idx & 63;
    ks[j][d] = (float)Vb[(size_t)j * QKVN + d];
  }
  __syncthreads();

  {
    int i = t >> 3, d8 = (t & 7) << 3;
    float4 a0 = {0.f, 0.f, 0.f, 0.f}, a1 = {0.f, 0.f, 0.f, 0.f};
#pragma unroll 4
    for (int j = 0; j < 128; ++j) {
      float p = ss[i][j];
      float4 v0 = *(const float4*)&ks[j][d8];
      float4 v1 = *(const float4*)&ks[j][d8 + 4];
      a0.x += p * v0.x; a0.y += p * v0.y; a0.z += p * v0.z; a0.w += p * v0.w;
      a1.x += p * v1.x; a1.y += p * v1.y; a1.z += p * v1.z; a1.w += p * v1.w;
    }
    _Float16* op = Ctx + (size_t)b * SEQ * HDIM + (size_t)(q0 + i) * HDIM + h * HEADD + d8;
    op[0] = (_Float16)a0.x; op[1] = (_Float16)a0.y;
    op[2] = (_Float16)a0.z; op[3] = (_Float16)a0.w;
    op[4] = (_Float16)a1.x; op[5] = (_Float16)a1.y;
    op[6] = (_Float16)a1.z; op[7] = (_Float16)a1.w;
  }
}

// ---------------- residual + layernorm (fp32, optional f16 copy) --------------
__global__ __launch_bounds__(256) void resid_ln_kernel(
    const float* __restrict__ X, const float* __restrict__ Y,
    const float* __restrict__ Gall, const float* __restrict__ Ball,
    const int* __restrict__ eid, float* __restrict__ Out,
    _Float16* __restrict__ Out16) {
  int row = blockIdx.x, b = blockIdx.y, t = threadIdx.x;
  int e = eid[b];
  const float* x = X + ((size_t)b * SEQ + row) * HDIM;
  const float* y = Y + ((size_t)b * SEQ + row) * HDIM;
  float* o = Out + ((size_t)b * SEQ + row) * HDIM;
  const float* g = Gall + (size_t)e * HDIM;
  const float* bb = Ball + (size_t)e * HDIM;

  __shared__ float buf[HDIM];
  __shared__ float red[256];

  float s = 0.f;
  for (int h = t; h < HDIM; h += 256) {
    float v = x[h] + y[h];
    buf[h] = v;
    s += v;
  }
  red[t] = s;
  __syncthreads();
  for (int off = 128; off > 0; off >>= 1) {
    if (t < off) red[t] += red[t + off];
    __syncthreads();
  }
  float mean = red[0] * (1.0f / HDIM);
  __syncthreads();

  float s2 = 0.f;
  for (int h = t; h < HDIM; h += 256) {
    float d = buf[h] - mean;
    s2 += d * d;
  }
  red[t] = s2;
  __syncthreads();
  for (int off = 128; off > 0; off >>= 1) {
    if (t < off) red[t] += red[t + off];
    __syncthreads();
  }
  float var = red[0] * (1.0f / HDIM);
  float rs = rsqrtf(var + 1e-12f);

  for (int h = t; h < HDIM; h += 256) {
    float v = (buf[h] - mean) * rs * g[h] + bb[h];
    o[h] = v;
    if (Out16) Out16[((size_t)b * SEQ + row) * HDIM + h] = (_Float16)v;
  }
}

// ------------------------------------------------------------------------------
extern "C" void kernel_launch(void* const* d_in, const int* in_sizes, int n_in,
                              void* d_out, int out_size, void* d_ws, size_t ws_size,
                              hipStream_t stream) {
  const float* hs   = (const float*)d_in[0];
  const float* mask = (const float*)d_in[1];
  const float* cen  = (const float*)d_in[2];
  const float* wq = (const float*)d_in[3];
  const float* wk = (const float*)d_in[4];
  const float* wv = (const float*)d_in[5];
  const float* wo = (const float*)d_in[6];
  const float* bq = (const float*)d_in[7];
  const float* bk = (const float*)d_in[8];
  const float* bv = (const float*)d_in[9];
  const float* bo = (const float*)d_in[10];
  const float* ln1g = (const float*)d_in[11];
  const float* ln1b = (const float*)d_in[12];
  const float* w1 = (const float*)d_in[13];
  const float* b1 = (const float*)d_in[14];
  const float* w2 = (const float*)d_in[15];
  const float* b2 = (const float*)d_in[16];
  const float* ln2g = (const float*)d_in[17];
  const float* ln2b = (const float*)d_in[18];
  float* out = (float*)d_out;

  const size_t sh = (size_t)SEQ * HDIM;

  char* p = (char*)d_ws;
  int* eid = (int*)p;                 p += 256;
  float* bqkv = (float*)p;            p += (size_t)NEXP * QKVN * 4;
  _Float16* Wqkvt = (_Float16*)p;     p += (size_t)NEXP * QKVN * HDIM * 2;
  _Float16* Wot = (_Float16*)p;       p += (size_t)NEXP * HDIM * HDIM * 2;
  _Float16* W1t = (_Float16*)p;       p += (size_t)NEXP * FFDIM * HDIM * 2;  // [E][3072][768]
  _Float16* W2t = (_Float16*)p;       p += (size_t)NEXP * HDIM * FFDIM * 2;  // [E][768][3072]
  _Float16* x16 = (_Float16*)p;       p += (size_t)NB * sh * 2;

  size_t fixed = (size_t)(p - (char*)d_ws);
  const size_t perS = (size_t)SEQ * QKVN * 2 + sh * 2 + sh * 4 + sh * 2 + (size_t)SEQ * FFDIM * 2;
  int CB = 64;
  while (CB > 1 && fixed + (size_t)CB * perS > ws_size) CB >>= 1;

  // region: qkv16 (f16 [CB][128][2304]) -> attout (f32 [CB][128][768]) -> w2out (f32)
  char* region = p;                   p += (size_t)CB * SEQ * QKVN * 2;
  _Float16* ctx16 = (_Float16*)p;     p += (size_t)CB * sh * 2;
  float* aof = (float*)p;             p += (size_t)CB * sh * 4;
  _Float16* ao16 = (_Float16*)p;      p += (size_t)CB * sh * 2;
  _Float16* ff16 = (_Float16*)p;      p += (size_t)CB * SEQ * FFDIM * 2;

  route_kernel<<<NB, 256, 0, stream>>>(hs, cen, eid);
  cvt_f16<<<(int)((NB * sh / 4 + 255) / 256), 256, 0, stream>>>(hs, x16, (int)(NB * sh / 4));
  concat_bias<<<(NEXP * QKVN + 255) / 256, 256, 0, stream>>>(bq, bk, bv, bqkv);
  transpose_cvt<<<dim3(HDIM / 32, HDIM / 32, NEXP), 256, 0, stream>>>(
      wq, Wqkvt + 0 * HDIM * HDIM, HDIM, HDIM, (size_t)QKVN * HDIM);
  transpose_cvt<<<dim3(HDIM / 32, HDIM / 32, NEXP), 256, 0, stream>>>(
      wk, Wqkvt + 1 * HDIM * HDIM, HDIM, HDIM, (size_t)QKVN * HDIM);
  transpose_cvt<<<dim3(HDIM / 32, HDIM / 32, NEXP), 256, 0, stream>>>(
      wv, Wqkvt + 2 * HDIM * HDIM, HDIM, HDIM, (size_t)QKVN * HDIM);
  transpose_cvt<<<dim3(HDIM / 32, HDIM / 32, NEXP), 256, 0, stream>>>(
      wo, Wot, HDIM, HDIM, (size_t)HDIM * HDIM);
  transpose_cvt<<<dim3(FFDIM / 32, HDIM / 32, NEXP), 256, 0, stream>>>(
      w1, W1t, HDIM, FFDIM, (size_t)FFDIM * HDIM);
  transpose_cvt<<<dim3(HDIM / 32, FFDIM / 32, NEXP), 256, 0, stream>>>(
      w2, W2t, FFDIM, HDIM, (size_t)HDIM * FFDIM);

  for (int b0 = 0; b0 < NB; b0 += CB) {
    const int* ec = eid + b0;
    // QKV fused GEMM -> region (f16 [CB][128][2304])
    gemm_mfma<1, 0><<<dim3(QKVN / 128, 1, CB), 256, 0, stream>>>(
        x16 + (size_t)b0 * sh, Wqkvt, bqkv, ec, region, HDIM, QKVN);
    // attention -> ctx16
    attn_kernel<<<dim3(SEQ / 32, NHEAD, CB), 256, 0, stream>>>(
        (const _Float16*)region, mask, b0, ctx16);
    // wo GEMM -> attout (f32, reuses region)
    gemm_mfma<0, 0><<<dim3(HDIM / 128, 1, CB), 256, 0, stream>>>(
        ctx16, Wot, bo, ec, region, HDIM, HDIM);
    // LN1 -> aof (f32) + ao16 (f16)
    resid_ln_kernel<<<dim3(SEQ, CB), 256, 0, stream>>>(
        hs + (size_t)b0 * sh, (const float*)region, ln1g, ln1b, ec, aof, ao16);
    // FFN
    gemm_mfma<1, 1><<<dim3(FFDIM / 128, 1, CB), 256, 0, stream>>>(
        ao16, W1t, b1, ec, ff16, HDIM, FFDIM);
    gemm_mfma<0, 0><<<dim3(HDIM / 128, 1, CB), 256, 0, stream>>>(
        ff16, W2t, b2, ec, region, FFDIM, HDIM);
    // LN2 -> out
    resid_ln_kernel<<<dim3(SEQ, CB), 256, 0, stream>>>(
        aof, (const float*)region, ln2g, ln2b, ec, out + (size_t)b0 * sh, (_Float16*)nullptr);
  }
}

// Round 3
// 549.119 us; speedup vs baseline: 3.7289x; 1.1919x over previous
//
#include <hip/hip_runtime.h>
#include <hip/hip_bf16.h>
#include <math.h>

#define HDIM 768
#define NHEAD 12
#define HEADD 64
#define FFDIM 3072
#define NEXP 4
#define SEQ 128
#define NB 64
#define QKVN 2304

typedef __attribute__((ext_vector_type(8))) _Float16 f16x8;
typedef __attribute__((ext_vector_type(4))) float f32x4;

__device__ __forceinline__ float gelu_tanh(float x) {
  float x3 = x * x * x;
  return 0.5f * x * (1.0f + tanhf(0.7978845608028654f * (x + 0.044715f * x3)));
}

__device__ __forceinline__ void gld_lds16(const void* g, void* l) {
  __builtin_amdgcn_global_load_lds(
      (const __attribute__((address_space(1))) unsigned int*)g,
      (__attribute__((address_space(3))) unsigned int*)l, 16, 0, 0);
}

// ---------------- routing ----------------------------------------------------
__global__ __launch_bounds__(256) void route_kernel(
    const float* __restrict__ hs, const float* __restrict__ centers,
    int* __restrict__ eid) {
  int b = blockIdx.x, t = threadIdx.x;
  __shared__ float hp[HDIM];
  __shared__ float dist[NEXP];
  const float* xb = hs + (size_t)b * SEQ * HDIM;
  for (int h = t; h < HDIM; h += 256) {
    float s = 0.f;
    for (int sq = 0; sq < SEQ; ++sq) s += xb[(size_t)sq * HDIM + h];
    hp[h] = s * (1.0f / SEQ);
  }
  if (t < NEXP) dist[t] = 0.f;
  __syncthreads();
  float pe[NEXP] = {0.f, 0.f, 0.f, 0.f};
  for (int h = t; h < HDIM; h += 256) {
    float v = hp[h];
#pragma unroll
    for (int e = 0; e < NEXP; ++e) {
      float d = v - centers[e * HDIM + h];
      pe[e] += d * d;
    }
  }
#pragma unroll
  for (int e = 0; e < NEXP; ++e) atomicAdd(&dist[e], pe[e]);
  __syncthreads();
  if (t == 0) {
    int best = 0; float bv = dist[0];
    for (int e = 1; e < NEXP; ++e) if (dist[e] < bv) { bv = dist[e]; best = e; }
    eid[b] = best;
  }
}

// ---------------- fp32 -> f16 elementwise ------------------------------------
__global__ __launch_bounds__(256) void cvt_f16(const float* __restrict__ in,
                                               _Float16* __restrict__ out, int n4) {
  int i = blockIdx.x * 256 + threadIdx.x;
  if (i < n4) {
    float4 v = ((const float4*)in)[i];
    out[i * 4 + 0] = (_Float16)v.x;
    out[i * 4 + 1] = (_Float16)v.y;
    out[i * 4 + 2] = (_Float16)v.z;
    out[i * 4 + 3] = (_Float16)v.w;
  }
}

// ---------------- weight transpose+convert: [E][K][N] f32 -> [E][N][K] f16 ----
__global__ __launch_bounds__(256) void transpose_cvt(
    const float* __restrict__ in, _Float16* __restrict__ out,
    int K, int N, size_t outEstride) {
  __shared__ float tile[32][33];
  int e = blockIdx.z;
  const float* ip = in + (size_t)e * K * N;
  _Float16* op = out + (size_t)e * outEstride;
  int nb = blockIdx.x * 32, kb = blockIdx.y * 32;
  int tx = threadIdx.x & 31, ty = threadIdx.x >> 5;
  for (int i = ty; i < 32; i += 8)
    tile[i][tx] = ip[(size_t)(kb + i) * N + nb + tx];
  __syncthreads();
  for (int i = ty; i < 32; i += 8)
    op[(size_t)(nb + i) * K + kb + tx] = (_Float16)tile[tx][i];
}

__global__ __launch_bounds__(256) void concat_bias(
    const float* __restrict__ bq, const float* __restrict__ bk,
    const float* __restrict__ bv, float* __restrict__ bqkv) {
  int i = blockIdx.x * 256 + threadIdx.x;
  if (i < NEXP * QKVN) {
    int e = i / QKVN, n = i % QKVN;
    float v = (n < HDIM) ? bq[e * HDIM + n]
            : (n < 2 * HDIM) ? bk[e * HDIM + n - HDIM]
                             : bv[e * HDIM + n - 2 * HDIM];
    bqkv[i] = v;
  }
}

// ---------------- MFMA GEMM: C[b] = A[b] @ Wt[eid[b]]^T + bias ----------------
template <int OUT_F16, int GELU>
__global__ __launch_bounds__(256) void gemm_mfma(
    const _Float16* __restrict__ A, const _Float16* __restrict__ Wt,
    const float* __restrict__ Ball, const int* __restrict__ eid,
    void* __restrict__ Cv, int K, int N) {
  int b = blockIdx.z;
  int e = eid[b];
  int col0 = blockIdx.x * 128;
  int t = threadIdx.x;
  int lane = t & 63, w = t >> 6;
  int quad = lane >> 4, l16 = lane & 15;
  int wr = (w >> 1) * 64, wc = (w & 1) * 64;

  __shared__ __align__(16) _Float16 As[128 * 32];
  __shared__ __align__(16) _Float16 Bs[128 * 32];

  const _Float16* Ab = A + (size_t)b * SEQ * K;
  const _Float16* Wb = Wt + (size_t)e * N * K + (size_t)col0 * K;

  int e0 = t * 8, e1 = 2048 + t * 8;
  int m0 = e0 >> 5, k0e = e0 & 31;
  int m1 = e1 >> 5, k1e = e1 & 31;
  const _Float16* ga0 = Ab + (size_t)m0 * K + k0e;
  const _Float16* ga1 = Ab + (size_t)m1 * K + k1e;
  const _Float16* gb0 = Wb + (size_t)m0 * K + k0e;
  const _Float16* gb1 = Wb + (size_t)m1 * K + k1e;
  _Float16* lA0 = &As[e0]; _Float16* lA1 = &As[e1];
  _Float16* lB0 = &Bs[e0]; _Float16* lB1 = &Bs[e1];

  f32x4 acc[4][4];
#pragma unroll
  for (int i = 0; i < 4; ++i)
#pragma unroll
    for (int j = 0; j < 4; ++j) acc[i][j] = (f32x4){0.f, 0.f, 0.f, 0.f};

  for (int kk = 0; kk < K; kk += 32) {
    gld_lds16(ga0 + kk, lA0);
    gld_lds16(ga1 + kk, lA1);
    gld_lds16(gb0 + kk, lB0);
    gld_lds16(gb1 + kk, lB1);
    __syncthreads();
    f16x8 af[4], bf[4];
#pragma unroll
    for (int i = 0; i < 4; ++i)
      af[i] = *(const f16x8*)&As[(wr + i * 16 + l16) * 32 + quad * 8];
#pragma unroll
    for (int i = 0; i < 4; ++i)
      bf[i] = *(const f16x8*)&Bs[(wc + i * 16 + l16) * 32 + quad * 8];
#pragma unroll
    for (int i = 0; i < 4; ++i)
#pragma unroll
      for (int j = 0; j < 4; ++j)
        acc[i][j] = __builtin_amdgcn_mfma_f32_16x16x32_f16(af[i], bf[j], acc[i][j], 0, 0, 0);
    __syncthreads();
  }

  const float* bias = Ball + (size_t)e * N;
  float* Cf = (float*)Cv + (size_t)b * SEQ * N;
  _Float16* Ch = (_Float16*)Cv + (size_t)b * SEQ * N;
#pragma unroll
  for (int i = 0; i < 4; ++i) {
#pragma unroll
    for (int j = 0; j < 4; ++j) {
      int col = col0 + wc + j * 16 + l16;
      float bv = bias[col];
#pragma unroll
      for (int r = 0; r < 4; ++r) {
        int row = wr + i * 16 + quad * 4 + r;
        float v = acc[i][j][r] + bv;
        if (GELU) v = gelu_tanh(v);
        if (OUT_F16) Ch[(size_t)row * N + col] = (_Float16)v;
        else Cf[(size_t)row * N + col] = v;
      }
    }
  }
}

// ---------------- MFMA attention: one block per (head, sample) ----------------
// QK^T (bt-GEMM), register softmax via shfl_xor over l16, PV via V^T in LDS.
__global__ __launch_bounds__(256) void attn_mfma(
    const _Float16* __restrict__ QKV, const float* __restrict__ mask,
    int b0, _Float16* __restrict__ Ctx) {
  int h = blockIdx.x, b = blockIdx.y;
  int t = threadIdx.x;
  int w = t >> 6, lane = t & 63, quad = lane >> 4, l16 = lane & 15;

  __shared__ __align__(16) char smem[54784];
  _Float16* Qs = (_Float16*)smem;                 // [128][72]
  _Float16* Ks = (_Float16*)(smem + 18432);       // [128][72]
  _Float16* Ps = (_Float16*)smem;                 // [128][136] (overlaps Qs+Ks)
  _Float16* Vt = (_Float16*)(smem + 36864);       // [64][136]
  float* mrow = (float*)(smem + 54272);           // [128]

  const _Float16* Qb = QKV + (size_t)b * SEQ * QKVN + h * HEADD;
  const _Float16* Kb = Qb + HDIM;
  const _Float16* Vb = Qb + 2 * HDIM;

  // stage Q, K (rows K-contig, stride 72 f16)
#pragma unroll
  for (int it = 0; it < 4; ++it) {
    int chunk = t + it * 256;
    int row = chunk >> 3, c = chunk & 7;
    *(f16x8*)&Qs[row * 72 + c * 8] = *(const f16x8*)(Qb + (size_t)row * QKVN + c * 8);
    *(f16x8*)&Ks[row * 72 + c * 8] = *(const f16x8*)(Kb + (size_t)row * QKVN + c * 8);
  }
  // V: load row pairs, write transposed (packed u32) into Vt [64][136]
  {
    int vc = t & 7, vjp0 = t >> 3;
#pragma unroll
    for (int it = 0; it < 2; ++it) {
      int jp = vjp0 + it * 32;
      f16x8 v0 = *(const f16x8*)(Vb + (size_t)(2 * jp) * QKVN + vc * 8);
      f16x8 v1 = *(const f16x8*)(Vb + (size_t)(2 * jp + 1) * QKVN + vc * 8);
#pragma unroll
      for (int i = 0; i < 8; ++i) {
        int d = vc * 8 + i;
        unsigned ua = __builtin_bit_cast(unsigned short, (_Float16)v0[i]);
        unsigned ub = __builtin_bit_cast(unsigned short, (_Float16)v1[i]);
        ((unsigned*)Vt)[d * 68 + jp] = ua | (ub << 16);
      }
    }
  }
  if (t < SEQ) mrow[t] = mask[(size_t)(b0 + b) * SEQ + t];
  __syncthreads();

  // ---- QK^T: wave w covers q-rows [w*32, w*32+32) ----
  int m0 = w * 32;
  f32x4 accs[2][8];
#pragma unroll
  for (int i = 0; i < 2; ++i)
#pragma unroll
    for (int j = 0; j < 8; ++j) accs[i][j] = (f32x4){0.f, 0.f, 0.f, 0.f};

#pragma unroll
  for (int ks = 0; ks < 2; ++ks) {
    int k0 = ks * 32 + quad * 8;
    f16x8 af[2], bf[8];
#pragma unroll
    for (int i = 0; i < 2; ++i)
      af[i] = *(const f16x8*)&Qs[(m0 + i * 16 + l16) * 72 + k0];
#pragma unroll
    for (int j = 0; j < 8; ++j)
      bf[j] = *(const f16x8*)&Ks[(j * 16 + l16) * 72 + k0];
#pragma unroll
    for (int i = 0; i < 2; ++i)
#pragma unroll
      for (int j = 0; j < 8; ++j)
        accs[i][j] = __builtin_amdgcn_mfma_f32_16x16x32_f16(af[i], bf[j], accs[i][j], 0, 0, 0);
  }
  __syncthreads();   // Qs/Ks reads complete; region becomes Ps

  // ---- softmax in C-layout registers ----
  float mv[8];
#pragma unroll
  for (int j = 0; j < 8; ++j) mv[j] = mrow[j * 16 + l16];

  float linv[2][4];
#pragma unroll
  for (int i = 0; i < 2; ++i) {
#pragma unroll
    for (int j = 0; j < 8; ++j)
#pragma unroll
      for (int r = 0; r < 4; ++r)
        accs[i][j][r] = accs[i][j][r] * 0.125f + mv[j];
#pragma unroll
    for (int r = 0; r < 4; ++r) {
      float m = accs[i][0][r];
#pragma unroll
      for (int j = 1; j < 8; ++j) m = fmaxf(m, accs[i][j][r]);
      m = fmaxf(m, __shfl_xor(m, 1));
      m = fmaxf(m, __shfl_xor(m, 2));
      m = fmaxf(m, __shfl_xor(m, 4));
      m = fmaxf(m, __shfl_xor(m, 8));
      float sum = 0.f;
#pragma unroll
      for (int j = 0; j < 8; ++j) {
        float p = __expf(accs[i][j][r] - m);
        accs[i][j][r] = p;
        sum += p;
      }
      sum += __shfl_xor(sum, 1);
      sum += __shfl_xor(sum, 2);
      sum += __shfl_xor(sum, 4);
      sum += __shfl_xor(sum, 8);
      linv[i][r] = 1.f / sum;
    }
    // store unnormalized exp as f16 into Ps
    int rowb = m0 + i * 16 + quad * 4;
#pragma unroll
    for (int j = 0; j < 8; ++j)
#pragma unroll
      for (int r = 0; r < 4; ++r)
        Ps[(rowb + r) * 136 + j * 16 + l16] = (_Float16)accs[i][j][r];
  }
  __syncthreads();   // Ps + Vt ready

  // ---- PV ----
  f32x4 acco[2][4];
#pragma unroll
  for (int i = 0; i < 2; ++i)
#pragma unroll
    for (int j = 0; j < 4; ++j) acco[i][j] = (f32x4){0.f, 0.f, 0.f, 0.f};

#pragma unroll
  for (int ks = 0; ks < 4; ++ks) {
    int k0 = ks * 32 + quad * 8;
    f16x8 pa[2], vf[4];
#pragma unroll
    for (int i = 0; i < 2; ++i)
      pa[i] = *(const f16x8*)&Ps[(m0 + i * 16 + l16) * 136 + k0];
#pragma unroll
    for (int j = 0; j < 4; ++j)
      vf[j] = *(const f16x8*)&Vt[(j * 16 + l16) * 136 + k0];
#pragma unroll
    for (int i = 0; i < 2; ++i)
#pragma unroll
      for (int j = 0; j < 4; ++j)
        acco[i][j] = __builtin_amdgcn_mfma_f32_16x16x32_f16(pa[i], vf[j], acco[i][j], 0, 0, 0);
  }

  // ---- epilogue: normalize rows, write ctx f16 ----
  _Float16* Cb = Ctx + (size_t)b * SEQ * HDIM + h * HEADD;
#pragma unroll
  for (int i = 0; i < 2; ++i)
#pragma unroll
    for (int j = 0; j < 4; ++j)
#pragma unroll
      for (int r = 0; r < 4; ++r) {
        int row = m0 + i * 16 + quad * 4 + r;
        int d = j * 16 + l16;
        Cb[(size_t)row * HDIM + d] = (_Float16)(acco[i][j][r] * linv[i][r]);
      }
}

// ---------------- residual + layernorm (fp32, optional f16 copy) --------------
__global__ __launch_bounds__(256) void resid_ln_kernel(
    const float* __restrict__ X, const float* __restrict__ Y,
    const float* __restrict__ Gall, const float* __restrict__ Ball,
    const int* __restrict__ eid, float* __restrict__ Out,
    _Float16* __restrict__ Out16) {
  int row = blockIdx.x, b = blockIdx.y, t = threadIdx.x;
  int e = eid[b];
  const float* x = X + ((size_t)b * SEQ + row) * HDIM;
  const float* y = Y + ((size_t)b * SEQ + row) * HDIM;
  float* o = Out + ((size_t)b * SEQ + row) * HDIM;
  const float* g = Gall + (size_t)e * HDIM;
  const float* bb = Ball + (size_t)e * HDIM;

  __shared__ float buf[HDIM];
  __shared__ float red[256];

  float s = 0.f;
  for (int h = t; h < HDIM; h += 256) {
    float v = x[h] + y[h];
    buf[h] = v;
    s += v;
  }
  red[t] = s;
  __syncthreads();
  for (int off = 128; off > 0; off >>= 1) {
    if (t < off) red[t] += red[t + off];
    __syncthreads();
  }
  float mean = red[0] * (1.0f / HDIM);
  __syncthreads();

  float s2 = 0.f;
  for (int h = t; h < HDIM; h += 256) {
    float d = buf[h] - mean;
    s2 += d * d;
  }
  red[t] = s2;
  __syncthreads();
  for (int off = 128; off > 0; off >>= 1) {
    if (t < off) red[t] += red[t + off];
    __syncthreads();
  }
  float var = red[0] * (1.0f / HDIM);
  float rs = rsqrtf(var + 1e-12f);

  for (int h = t; h < HDIM; h += 256) {
    float v = (buf[h] - mean) * rs * g[h] + bb[h];
    o[h] = v;
    if (Out16) Out16[((size_t)b * SEQ + row) * HDIM + h] = (_Float16)v;
  }
}

// ------------------------------------------------------------------------------
extern "C" void kernel_launch(void* const* d_in, const int* in_sizes, int n_in,
                              void* d_out, int out_size, void* d_ws, size_t ws_size,
                              hipStream_t stream) {
  const float* hs   = (const float*)d_in[0];
  const float* mask = (const float*)d_in[1];
  const float* cen  = (const float*)d_in[2];
  const float* wq = (const float*)d_in[3];
  const float* wk = (const float*)d_in[4];
  const float* wv = (const float*)d_in[5];
  const float* wo = (const float*)d_in[6];
  const float* bq = (const float*)d_in[7];
  const float* bk = (const float*)d_in[8];
  const float* bv = (const float*)d_in[9];
  const float* bo = (const float*)d_in[10];
  const float* ln1g = (const float*)d_in[11];
  const float* ln1b = (const float*)d_in[12];
  const float* w1 = (const float*)d_in[13];
  const float* b1 = (const float*)d_in[14];
  const float* w2 = (const float*)d_in[15];
  const float* b2 = (const float*)d_in[16];
  const float* ln2g = (const float*)d_in[17];
  const float* ln2b = (const float*)d_in[18];
  float* out = (float*)d_out;

  const size_t sh = (size_t)SEQ * HDIM;

  char* p = (char*)d_ws;
  int* eid = (int*)p;                 p += 256;
  float* bqkv = (float*)p;            p += (size_t)NEXP * QKVN * 4;
  _Float16* Wqkvt = (_Float16*)p;     p += (size_t)NEXP * QKVN * HDIM * 2;
  _Float16* Wot = (_Float16*)p;       p += (size_t)NEXP * HDIM * HDIM * 2;
  _Float16* W1t = (_Float16*)p;       p += (size_t)NEXP * FFDIM * HDIM * 2;
  _Float16* W2t = (_Float16*)p;       p += (size_t)NEXP * HDIM * FFDIM * 2;
  _Float16* x16 = (_Float16*)p;       p += (size_t)NB * sh * 2;

  size_t fixed = (size_t)(p - (char*)d_ws);
  const size_t perS = (size_t)SEQ * QKVN * 2 + sh * 2 + sh * 4 + sh * 2 + (size_t)SEQ * FFDIM * 2;
  int CB = 64;
  while (CB > 1 && fixed + (size_t)CB * perS > ws_size) CB >>= 1;

  char* region = p;                   p += (size_t)CB * SEQ * QKVN * 2;
  _Float16* ctx16 = (_Float16*)p;     p += (size_t)CB * sh * 2;
  float* aof = (float*)p;             p += (size_t)CB * sh * 4;
  _Float16* ao16 = (_Float16*)p;      p += (size_t)CB * sh * 2;
  _Float16* ff16 = (_Float16*)p;      p += (size_t)CB * SEQ * FFDIM * 2;

  route_kernel<<<NB, 256, 0, stream>>>(hs, cen, eid);
  cvt_f16<<<(int)((NB * sh / 4 + 255) / 256), 256, 0, stream>>>(hs, x16, (int)(NB * sh / 4));
  concat_bias<<<(NEXP * QKVN + 255) / 256, 256, 0, stream>>>(bq, bk, bv, bqkv);
  transpose_cvt<<<dim3(HDIM / 32, HDIM / 32, NEXP), 256, 0, stream>>>(
      wq, Wqkvt + 0 * HDIM * HDIM, HDIM, HDIM, (size_t)QKVN * HDIM);
  transpose_cvt<<<dim3(HDIM / 32, HDIM / 32, NEXP), 256, 0, stream>>>(
      wk, Wqkvt + 1 * HDIM * HDIM, HDIM, HDIM, (size_t)QKVN * HDIM);
  transpose_cvt<<<dim3(HDIM / 32, HDIM / 32, NEXP), 256, 0, stream>>>(
      wv, Wqkvt + 2 * HDIM * HDIM, HDIM, HDIM, (size_t)QKVN * HDIM);
  transpose_cvt<<<dim3(HDIM / 32, HDIM / 32, NEXP), 256, 0, stream>>>(
      wo, Wot, HDIM, HDIM, (size_t)HDIM * HDIM);
  transpose_cvt<<<dim3(FFDIM / 32, HDIM / 32, NEXP), 256, 0, stream>>>(
      w1, W1t, HDIM, FFDIM, (size_t)FFDIM * HDIM);
  transpose_cvt<<<dim3(HDIM / 32, FFDIM / 32, NEXP), 256, 0, stream>>>(
      w2, W2t, FFDIM, HDIM, (size_t)HDIM * FFDIM);

  for (int b0 = 0; b0 < NB; b0 += CB) {
    const int* ec = eid + b0;
    gemm_mfma<1, 0><<<dim3(QKVN / 128, 1, CB), 256, 0, stream>>>(
        x16 + (size_t)b0 * sh, Wqkvt, bqkv, ec, region, HDIM, QKVN);
    attn_mfma<<<dim3(NHEAD, CB), 256, 0, stream>>>(
        (const _Float16*)region, mask, b0, ctx16);
    gemm_mfma<0, 0><<<dim3(HDIM / 128, 1, CB), 256, 0, stream>>>(
        ctx16, Wot, bo, ec, region, HDIM, HDIM);
    resid_ln_kernel<<<dim3(SEQ, CB), 256, 0, stream>>>(
        hs + (size_t)b0 * sh, (const float*)region, ln1g, ln1b, ec, aof, ao16);
    gemm_mfma<1, 1><<<dim3(FFDIM / 128, 1, CB), 256, 0, stream>>>(
        ao16, W1t, b1, ec, ff16, HDIM, FFDIM);
    gemm_mfma<0, 0><<<dim3(HDIM / 128, 1, CB), 256, 0, stream>>>(
        ff16, W2t, b2, ec, region, FFDIM, HDIM);
    resid_ln_kernel<<<dim3(SEQ, CB), 256, 0, stream>>>(
        aof, (const float*)region, ln2g, ln2b, ec, out + (size_t)b0 * sh, (_Float16*)nullptr);
  }
}